// Round 1
// 426.057 us; speedup vs baseline: 1.0818x; 1.0818x over previous
//
#include <hip/hip_runtime.h>
#include <stdint.h>
#include <string.h>

#define FEAT 512
#define HID 512
#define KNB 25
#define FS 27
#define NNODES 100000
#define ALPHA 0.2f

typedef short bf16x8 __attribute__((ext_vector_type(8)));
typedef float f32x4 __attribute__((ext_vector_type(4)));

__device__ __forceinline__ float bf2f(unsigned short u) {
    union { unsigned int i; float f; } x; x.i = ((unsigned int)u) << 16; return x.f;
}
__device__ __forceinline__ unsigned short f2bf(float f) {
    unsigned int x = __float_as_uint(f);
    unsigned int r = (x + 0x7fffu + ((x >> 16) & 1u)) >> 16;
    return (unsigned short)r;
}
// load element idx of a float array whose storage is fp32 (isf32) or bf16
__device__ __forceinline__ float ldf(const void* base, size_t idx, bool isf32) {
    return isf32 ? ((const float*)base)[idx] : bf2f(((const unsigned short*)base)[idx]);
}

// Decide whether float tensors are stored as fp32 (flag=1) or bf16 (flag=0).
__global__ void detect_dtype(const void* __restrict__ feat, int* __restrict__ flag) {
    __shared__ int cnt;
    if (threadIdx.x == 0) cnt = 0;
    __syncthreads();
    const unsigned short* u = (const unsigned short*)feat;
    int c = 0;
    for (int i = threadIdx.x; i < 2048; i += 256) {
        float av = fabsf(bf2f(u[i]));
        if (!(av < 1e4f)) c++;
    }
    atomicAdd(&cnt, c);
    __syncthreads();
    if (threadIdx.x == 0) *flag = (cnt > 16) ? 1 : 0;
}

// p[f] = sum_h W[f,h]*a2[h] ; q[f] = sum_h W[f,h]*a1[h]   (one wave per f)
__global__ void prep_pq(const void* __restrict__ W, const void* __restrict__ a_vec,
                        const int* __restrict__ flag,
                        float* __restrict__ p, float* __restrict__ q) {
    bool isf32 = (*flag != 0);
    int f = blockIdx.x;
    int lane = threadIdx.x;  // 0..63
    float accp = 0.f, accq = 0.f;
    #pragma unroll
    for (int j = 0; j < 8; ++j) {
        int h = lane * 8 + j;
        float wv = ldf(W, (size_t)f * HID + h, isf32);
        accq += wv * ldf(a_vec, h, isf32);
        accp += wv * ldf(a_vec, HID + h, isf32);
    }
    #pragma unroll
    for (int off = 32; off > 0; off >>= 1) {
        accp += __shfl_down(accp, off);
        accq += __shfl_down(accq, off);
    }
    if (lane == 0) { p[f] = accp; q[f] = accq; }
}

// M = U @ (U^T @ ones)  — length-27 vector
__global__ void prep_M(const void* __restrict__ U, const int* __restrict__ flag,
                       float* __restrict__ Mv) {
    __shared__ float cs[FS];
    bool isf32 = (*flag != 0);
    int t = threadIdx.x;
    if (t < FS) {
        float c = 0.f;
        for (int i = 0; i < FS; ++i) c += ldf(U, i * FS + t, isf32);
        cs[t] = c;
    }
    __syncthreads();
    if (t < FS) {
        float m = 0.f;
        for (int j = 0; j < FS; ++j) m += ldf(U, t * FS + j, isf32) * cs[j];
        Mv[t] = m;
    }
}

// Wt[n*FEAT + k] = bf16(W[k*HID + n])
__global__ void transposeW(const void* __restrict__ W, const int* __restrict__ flag,
                           unsigned short* __restrict__ Wt) {
    bool isf32 = (*flag != 0);
    int idx = blockIdx.x * blockDim.x + threadIdx.x;
    int n = idx >> 9, k = idx & (HID - 1);
    Wt[idx] = f2bf(ldf(W, (size_t)k * HID + n, isf32));
}

// Streaming pass over the whole node table: convert each row to bf16 (if input
// is fp32) and compute per-node scores sp[id]=row·p, sq[id]=row·q.
// One wave per row, 4 rows per block.
__global__ __launch_bounds__(256) void convert_score(
    const void* __restrict__ feat, const float* __restrict__ p,
    const float* __restrict__ q, const int* __restrict__ flag,
    unsigned short* __restrict__ featbf, float* __restrict__ sp,
    float* __restrict__ sq, int nRows) {
    bool isf32 = (*flag != 0);
    int wave = threadIdx.x >> 6, lane = threadIdx.x & 63;
    int row = blockIdx.x * 4 + wave;
    if (row >= nRows) return;
    float vals[8];
    if (isf32) {
        const float4* src = (const float4*)((const float*)feat + (size_t)row * FEAT) + lane * 2;
        float4 v0 = src[0], v1 = src[1];
        vals[0] = v0.x; vals[1] = v0.y; vals[2] = v0.z; vals[3] = v0.w;
        vals[4] = v1.x; vals[5] = v1.y; vals[6] = v1.z; vals[7] = v1.w;
        unsigned short o[8];
        #pragma unroll
        for (int j = 0; j < 8; ++j) o[j] = f2bf(vals[j]);
        *(uint4*)(&featbf[(size_t)row * FEAT + lane * 8]) = *(const uint4*)o;
    } else {
        uint4 v = *((const uint4*)((const unsigned short*)feat + (size_t)row * FEAT) + lane);
        unsigned int w4[4] = {v.x, v.y, v.z, v.w};
        #pragma unroll
        for (int j = 0; j < 4; ++j) {
            vals[2 * j]     = __uint_as_float(w4[j] << 16);
            vals[2 * j + 1] = __uint_as_float(w4[j] & 0xffff0000u);
        }
    }
    float accp = 0.f, accq = 0.f;
    const float* pv = p + lane * 8;
    const float* qv = q + lane * 8;
    #pragma unroll
    for (int j = 0; j < 8; ++j) { accp += vals[j] * pv[j]; accq += vals[j] * qv[j]; }
    #pragma unroll
    for (int off = 32; off > 0; off >>= 1) {
        accp += __shfl_down(accp, off);
        accq += __shfl_down(accq, off);
    }
    if (lane == 0) { sp[row] = accp; sq[row] = accq; }
}

// Light gather: one wave per central node. Scores are precomputed; weights are
// formed in-lane, broadcast via readlane (scalar base addresses), and the
// weighted bf16 row sum accumulates 8 features per lane. No LDS, no barriers.
__global__ __launch_bounds__(256) void attn_gather2(
    const void* __restrict__ feat, const unsigned short* __restrict__ featbf,
    const int* __restrict__ nodes, const int* __restrict__ neigh,
    const float* __restrict__ sp, const float* __restrict__ sq,
    const float* __restrict__ Mv, const int* __restrict__ flag,
    unsigned short* __restrict__ g, int B) {
    bool isf32 = (*flag != 0);
    const unsigned short* F = isf32 ? featbf : (const unsigned short*)feat;
    int wave = threadIdx.x >> 6, lane = threadIdx.x & 63;
    int b = blockIdx.x * 4 + wave;
    if (b >= B) return;
    int id = 0; float e = 0.f;
    if (lane < KNB) {
        id = neigh[(size_t)b * KNB + lane];
        float l = sq[nodes[b]] + sp[id];
        float lr = l > 0.f ? l : ALPHA * l;
        e = __expf(-lr);
    }
    float Z = e;  // lanes >= KNB hold 0
    #pragma unroll
    for (int off = 16; off > 0; off >>= 1) Z += __shfl_down(Z, off);
    Z = __shfl(Z, 0);
    float w = (lane < KNB) ? e * (1.f / Z) * Mv[lane + 1] : 0.f;
    float acc[8] = {0.f, 0.f, 0.f, 0.f, 0.f, 0.f, 0.f, 0.f};
    #pragma unroll
    for (int k = 0; k < KNB; ++k) {
        int idk = __builtin_amdgcn_readlane(id, k);
        float wk = __uint_as_float((unsigned int)__builtin_amdgcn_readlane(__float_as_int(w), k));
        uint4 v = *((const uint4*)(F + (size_t)idk * FEAT) + lane);
        unsigned int w4[4] = {v.x, v.y, v.z, v.w};
        #pragma unroll
        for (int j = 0; j < 4; ++j) {
            acc[2 * j]     += wk * __uint_as_float(w4[j] << 16);
            acc[2 * j + 1] += wk * __uint_as_float(w4[j] & 0xffff0000u);
        }
    }
    unsigned short o[8];
    #pragma unroll
    for (int j = 0; j < 8; ++j) o[j] = f2bf(acc[j]);
    *(uint4*)(&g[(size_t)b * FEAT + lane * 8]) = *(const uint4*)o;
}

// Legacy fallback path (used only when workspace is too small for the bf16
// table): one block per central node, scores + gather fused.
__global__ __launch_bounds__(256) void attn_gather(
    const void* __restrict__ feat, const int* __restrict__ nodes,
    const int* __restrict__ neigh, const float* __restrict__ p,
    const float* __restrict__ q, const float* __restrict__ Mv,
    const int* __restrict__ flag, unsigned short* __restrict__ g) {
    __shared__ __attribute__((aligned(16))) unsigned short ldsF[KNB * FEAT];
    __shared__ float ldsS[KNB + 1];
    bool isf32 = (*flag != 0);
    int b = blockIdx.x;
    int t = threadIdx.x;
    int wave = t >> 6, lane = t & 63;
    for (int r = wave; r < KNB + 1; r += 4) {
        int id = (r == 0) ? nodes[b] : neigh[(size_t)b * KNB + (r - 1)];
        float vals[8];
        if (isf32) {
            const float4* row = (const float4*)((const float*)feat + (size_t)id * FEAT) + lane * 2;
            float4 v0 = row[0], v1 = row[1];
            vals[0] = v0.x; vals[1] = v0.y; vals[2] = v0.z; vals[3] = v0.w;
            vals[4] = v1.x; vals[5] = v1.y; vals[6] = v1.z; vals[7] = v1.w;
        } else {
            uint4 v = *((const uint4*)((const unsigned short*)feat + (size_t)id * FEAT) + lane);
            unsigned int w4[4] = {v.x, v.y, v.z, v.w};
            #pragma unroll
            for (int j = 0; j < 4; ++j) {
                vals[2 * j]     = bf2f((unsigned short)(w4[j] & 0xffffu));
                vals[2 * j + 1] = bf2f((unsigned short)(w4[j] >> 16));
            }
        }
        if (r > 0) {
            unsigned short o[8];
            #pragma unroll
            for (int j = 0; j < 8; ++j) o[j] = f2bf(vals[j]);
            *(uint4*)(&ldsF[(r - 1) * FEAT + lane * 8]) = *(const uint4*)o;
        }
        const float* vec = ((r == 0) ? q : p) + lane * 8;
        float acc = 0.f;
        #pragma unroll
        for (int j = 0; j < 8; ++j) acc += vals[j] * vec[j];
        #pragma unroll
        for (int off = 32; off > 0; off >>= 1) acc += __shfl_down(acc, off);
        if (lane == 0) ldsS[r] = acc;
    }
    __syncthreads();
    float s0 = ldsS[0];
    float w[KNB];
    float Z = 0.f;
    #pragma unroll
    for (int k = 0; k < KNB; ++k) {
        float l = s0 + ldsS[k + 1];
        float lr = l > 0.f ? l : ALPHA * l;
        float e = __expf(-lr);
        w[k] = e;
        Z += e;
    }
    float inv = 1.f / Z;
    #pragma unroll
    for (int k = 0; k < KNB; ++k) w[k] *= inv * Mv[k + 1];
    float acc0 = 0.f, acc1 = 0.f;
    #pragma unroll
    for (int k = 0; k < KNB; ++k) {
        unsigned int v = *(const unsigned int*)(&ldsF[k * FEAT + 2 * t]);
        acc0 += w[k] * bf2f((unsigned short)(v & 0xffffu));
        acc1 += w[k] * bf2f((unsigned short)(v >> 16));
    }
    unsigned int o = ((unsigned int)f2bf(acc1) << 16) | (unsigned int)f2bf(acc0);
    *(unsigned int*)(&g[(size_t)b * FEAT + 2 * t]) = o;
}

// out[m,n] = relu( sum_k G[m,k] * Wt[n,k] ). 64x64 tile, BK=64, bf16 MFMA.
__global__ __launch_bounds__(256) void gemm_relu(
    const unsigned short* __restrict__ G, const unsigned short* __restrict__ Wt,
    const int* __restrict__ flag, void* __restrict__ out, int M) {
    __shared__ __attribute__((aligned(16))) unsigned short As[64 * 72];
    __shared__ __attribute__((aligned(16))) unsigned short Bs[64 * 72];
    bool isf32 = (*flag != 0);
    int t = threadIdx.x;
    int mBase = blockIdx.y * 64;
    int nBase = blockIdx.x * 64;
    int wave = t >> 6, lane = t & 63;
    int mOff = (wave & 1) * 32, nOff = (wave >> 1) * 32;
    f32x4 acc00 = {0.f, 0.f, 0.f, 0.f}, acc01 = {0.f, 0.f, 0.f, 0.f};
    f32x4 acc10 = {0.f, 0.f, 0.f, 0.f}, acc11 = {0.f, 0.f, 0.f, 0.f};
    int lr = t >> 2;
    int seg = (t & 3) * 16;
    int fr = lane & 15, quad = lane >> 4;
    for (int k0 = 0; k0 < FEAT; k0 += 64) {
        uint4 av0 = {0u, 0u, 0u, 0u}, av1 = {0u, 0u, 0u, 0u};
        int gr = mBase + lr;
        if (gr < M) {
            const unsigned short* s = G + (size_t)gr * FEAT + k0 + seg;
            av0 = *(const uint4*)s;
            av1 = *(const uint4*)(s + 8);
        }
        *(uint4*)(&As[lr * 72 + seg]) = av0;
        *(uint4*)(&As[lr * 72 + seg + 8]) = av1;
        const unsigned short* bs = Wt + (size_t)(nBase + lr) * FEAT + k0 + seg;
        *(uint4*)(&Bs[lr * 72 + seg]) = *(const uint4*)bs;
        *(uint4*)(&Bs[lr * 72 + seg + 8]) = *(const uint4*)(bs + 8);
        __syncthreads();
        #pragma unroll
        for (int kk = 0; kk < 64; kk += 32) {
            bf16x8 a0 = *(const bf16x8*)(&As[(mOff + fr) * 72 + kk + quad * 8]);
            bf16x8 a1 = *(const bf16x8*)(&As[(mOff + 16 + fr) * 72 + kk + quad * 8]);
            bf16x8 b0 = *(const bf16x8*)(&Bs[(nOff + fr) * 72 + kk + quad * 8]);
            bf16x8 b1 = *(const bf16x8*)(&Bs[(nOff + 16 + fr) * 72 + kk + quad * 8]);
            acc00 = __builtin_amdgcn_mfma_f32_16x16x32_bf16(a0, b0, acc00, 0, 0, 0);
            acc01 = __builtin_amdgcn_mfma_f32_16x16x32_bf16(a0, b1, acc01, 0, 0, 0);
            acc10 = __builtin_amdgcn_mfma_f32_16x16x32_bf16(a1, b0, acc10, 0, 0, 0);
            acc11 = __builtin_amdgcn_mfma_f32_16x16x32_bf16(a1, b1, acc11, 0, 0, 0);
        }
        __syncthreads();
    }
    int col = lane & 15, qr = (lane >> 4) * 4;
    #pragma unroll
    for (int sel = 0; sel < 4; ++sel) {
        f32x4 a = (sel == 0) ? acc00 : (sel == 1) ? acc01 : (sel == 2) ? acc10 : acc11;
        int mt = sel >> 1, nt = sel & 1;
        #pragma unroll
        for (int i = 0; i < 4; ++i) {
            int row = mBase + mOff + mt * 16 + qr + i;
            if (row < M) {
                int cn = nBase + nOff + nt * 16 + col;
                float v = a[i];
                v = v > 0.f ? v : 0.f;
                size_t off = (size_t)row * HID + cn;
                if (isf32) ((float*)out)[off] = v;
                else ((unsigned short*)out)[off] = f2bf(v);
            }
        }
    }
}

extern "C" void kernel_launch(void* const* d_in, const int* in_sizes, int n_in,
                              void* d_out, int out_size, void* d_ws, size_t ws_size,
                              hipStream_t stream) {
    const int* nodes = (const int*)d_in[0];
    const int* neigh = (const int*)d_in[1];
    const void* feat = d_in[2];
    const void* W = d_in[3];
    const void* a_vec = d_in[4];
    const void* U = d_in[5];
    int B = in_sizes[0];

    char* ws = (char*)d_ws;
    int* flag = (int*)ws;                                 // 4 B
    float* p = (float*)(ws + 256);                        // 512 f32
    float* q = (float*)(ws + 256 + 2048);                 // 512 f32
    float* Mv = (float*)(ws + 256 + 4096);                // 27 f32
    unsigned short* Wt = (unsigned short*)(ws + 4608);    // 512*512 bf16
    unsigned short* g = (unsigned short*)(ws + 4608 + (size_t)FEAT * HID * 2);  // B*512 bf16
    size_t gEnd = 4608 + (size_t)FEAT * HID * 2 + (size_t)B * FEAT * 2;
    float* sp = (float*)(ws + gEnd);                      // NNODES f32
    float* sq = (float*)(ws + gEnd + (size_t)NNODES * 4); // NNODES f32
    unsigned short* featbf = (unsigned short*)(ws + gEnd + (size_t)NNODES * 8);
    size_t need = gEnd + (size_t)NNODES * 8 + (size_t)NNODES * FEAT * 2;

    detect_dtype<<<1, 256, 0, stream>>>(feat, flag);
    prep_pq<<<FEAT, 64, 0, stream>>>(W, a_vec, flag, p, q);
    prep_M<<<1, 32, 0, stream>>>(U, flag, Mv);
    transposeW<<<(FEAT * HID) / 256, 256, 0, stream>>>(W, flag, Wt);
    if (ws_size >= need) {
        convert_score<<<(NNODES + 3) / 4, 256, 0, stream>>>(feat, p, q, flag, featbf, sp, sq, NNODES);
        attn_gather2<<<(B + 3) / 4, 256, 0, stream>>>(feat, featbf, nodes, neigh, sp, sq, Mv, flag, g, B);
    } else {
        attn_gather<<<B, 256, 0, stream>>>(feat, nodes, neigh, p, q, Mv, flag, g);
    }
    dim3 gg(HID / 64, (B + 63) / 64);
    gemm_relu<<<gg, 256, 0, stream>>>(g, Wt, flag, d_out, B);
}